// Round 4
// baseline (278.142 us; speedup 1.0000x reference)
//
#include <hip/hip_runtime.h>

#define VOCAB 128000
#define DIM 2048
#define NTOK 8192
#define RO_BLOCKS (VOCAB / 4)            // 4 rows/block, 1 row/wave
#define BM_WORDS 4096                    // 128000 bits -> 4000 dwords, round up

__device__ __forceinline__ float qclip(float w) {
  // jnp.clip(jnp.round(w), -128, 127); rintf == round-half-even == jnp.round
  return fminf(fmaxf(rintf(w), -128.0f), 127.0f);
}

// ---------------------------------------------------------------------------
// Preprocess: bitmap of vocab rows that appear in tokens.
// atomicOr is idempotent -> bitmap deterministic regardless of order.
// ---------------------------------------------------------------------------
__global__ __launch_bounds__(256) void bitmap_init_kernel(unsigned* __restrict__ bm) {
  const int i = blockIdx.x * 256 + threadIdx.x;
  if (i < BM_WORDS) bm[i] = 0u;
}

__global__ __launch_bounds__(256) void bitmap_build_kernel(
    const int* __restrict__ tokens, unsigned* __restrict__ bm) {
  const int t = blockIdx.x * 256 + threadIdx.x;
  if (t < NTOK) {
    const int row = tokens[t];
    atomicOr(&bm[row >> 5], 1u << (row & 31));
  }
}

// ---------------------------------------------------------------------------
// Fused main kernel.
//   blocks [0, NTOK):   embed: read W[tok] once -> write out_embed[t,:]
//                       AND out_readout[tok] (dot computed here; duplicate
//                       token blocks write bitwise-identical values).
//   blocks [NTOK, +RO_BLOCKS): readout rows NOT in tokens (bitmap skip).
// ---------------------------------------------------------------------------
__global__ __launch_bounds__(256) void fused_main_kernel(
    const float* __restrict__ W, const float* __restrict__ scales,
    const int* __restrict__ tokens, const float* __restrict__ x,
    const unsigned* __restrict__ bm, float* __restrict__ out_embed,
    float* __restrict__ out_readout) {
  const int b = blockIdx.x;
  const int wid = threadIdx.x >> 6;
  const int lane = threadIdx.x & 63;
  const float4* __restrict__ xv = reinterpret_cast<const float4*>(x);

  if (b < NTOK) {
    // ---- embed (+ dot for this token row) ----
    const int tok = tokens[b];
    const float srow = scales[tok];
    const float4* __restrict__ wrow =
        reinterpret_cast<const float4*>(W + (size_t)tok * DIM);
    float4* __restrict__ orow =
        reinterpret_cast<float4*>(out_embed + (size_t)b * DIM);

    // Each wave loads ALL of x (lane+64j covers DIM/4=512 float4s) -> global
    // absmax with an in-wave reduce only. The two x float4s this thread's dot
    // slice needs are xl[wid] and xl[wid+4] (tid = wid*64+lane).
    float4 xl[8];
    float m = 0.0f;
    #pragma unroll
    for (int k = 0; k < 8; ++k) {
      xl[k] = xv[lane + k * 64];
      m = fmaxf(m, fmaxf(fmaxf(fabsf(xl[k].x), fabsf(xl[k].y)),
                         fmaxf(fabsf(xl[k].z), fabsf(xl[k].w))));
    }
    #pragma unroll
    for (int off = 32; off > 0; off >>= 1) m = fmaxf(m, __shfl_xor(m, off, 64));
    const float scale = fmaxf(m / 127.0f, 1e-12f);
    const float rcp = 1.0f / scale;

    float part = 0.0f;
    #pragma unroll
    for (int k = 0; k < 2; ++k) {
      const int i = threadIdx.x + k * 256;   // == wid*64+lane + k*256
      float4 w4 = wrow[i];
      float4 xq = xl[wid + 4 * k];
      xq.x = fminf(fmaxf(rintf(xq.x * rcp), -128.0f), 127.0f) * scale;
      xq.y = fminf(fmaxf(rintf(xq.y * rcp), -128.0f), 127.0f) * scale;
      xq.z = fminf(fmaxf(rintf(xq.z * rcp), -128.0f), 127.0f) * scale;
      xq.w = fminf(fmaxf(rintf(xq.w * rcp), -128.0f), 127.0f) * scale;
      w4.x = qclip(w4.x);
      w4.y = qclip(w4.y);
      w4.z = qclip(w4.z);
      w4.w = qclip(w4.w);
      part += w4.x * xq.x + w4.y * xq.y + w4.z * xq.z + w4.w * xq.w;
      float4 r;
      r.x = w4.x * srow;
      r.y = w4.y * srow;
      r.z = w4.z * srow;
      r.w = w4.w * srow;
      orow[i] = r;
    }
    // block dot-sum: wave reduce -> LDS -> thread 0
    #pragma unroll
    for (int off = 32; off > 0; off >>= 1) part += __shfl_down(part, off, 64);
    __shared__ float spart[4];
    if (lane == 0) spart[wid] = part;
    __syncthreads();
    if (threadIdx.x == 0) {
      out_readout[tok] = (spart[0] + spart[1] + spart[2] + spart[3]) * srow;
    }
    return;
  }

  // ---- readout for rows not covered by embed blocks ----
  const int row = (b - NTOK) * 4 + wid;
  if ((bm[row >> 5] >> (row & 31)) & 1u) return;  // token row: embed block owns it

  float4 xl[8];
  float m = 0.0f;
  #pragma unroll
  for (int k = 0; k < 8; ++k) {
    xl[k] = xv[lane + k * 64];
    m = fmaxf(m, fmaxf(fmaxf(fabsf(xl[k].x), fabsf(xl[k].y)),
                       fmaxf(fabsf(xl[k].z), fabsf(xl[k].w))));
  }
  #pragma unroll
  for (int off = 32; off > 0; off >>= 1) m = fmaxf(m, __shfl_xor(m, off, 64));
  const float scale = fmaxf(m / 127.0f, 1e-12f);
  const float rcp = 1.0f / scale;
  #pragma unroll
  for (int k = 0; k < 8; ++k) {
    xl[k].x = fminf(fmaxf(rintf(xl[k].x * rcp), -128.0f), 127.0f) * scale;
    xl[k].y = fminf(fmaxf(rintf(xl[k].y * rcp), -128.0f), 127.0f) * scale;
    xl[k].z = fminf(fmaxf(rintf(xl[k].z * rcp), -128.0f), 127.0f) * scale;
    xl[k].w = fminf(fmaxf(rintf(xl[k].w * rcp), -128.0f), 127.0f) * scale;
  }

  const float4* __restrict__ wrow =
      reinterpret_cast<const float4*>(W + (size_t)row * DIM);
  float acc = 0.0f;
  #pragma unroll
  for (int k = 0; k < 8; ++k) {
    float4 w4 = wrow[lane + k * 64];
    acc += qclip(w4.x) * xl[k].x;
    acc += qclip(w4.y) * xl[k].y;
    acc += qclip(w4.z) * xl[k].z;
    acc += qclip(w4.w) * xl[k].w;
  }
  #pragma unroll
  for (int off = 32; off > 0; off >>= 1) acc += __shfl_down(acc, off, 64);
  if (lane == 0) out_readout[row] = acc * scales[row];
}

// ---------------------------------------------------------------------------
// Fallback (pure R2) if ws can't hold the bitmap.
// ---------------------------------------------------------------------------
__global__ __launch_bounds__(256) void fallback_fused_kernel(
    const float* __restrict__ W, const float* __restrict__ scales,
    const int* __restrict__ tokens, const float* __restrict__ x,
    float* __restrict__ out_embed, float* __restrict__ out_readout) {
  const int b = blockIdx.x;
  if (b < NTOK) {
    const int tok = tokens[b];
    const float s = scales[tok];
    const float4* __restrict__ wrow =
        reinterpret_cast<const float4*>(W + (size_t)tok * DIM);
    float4* __restrict__ orow =
        reinterpret_cast<float4*>(out_embed + (size_t)b * DIM);
    #pragma unroll
    for (int k = 0; k < 2; ++k) {
      const int i = threadIdx.x + k * 256;
      float4 w4 = wrow[i];
      float4 r;
      r.x = qclip(w4.x) * s;
      r.y = qclip(w4.y) * s;
      r.z = qclip(w4.z) * s;
      r.w = qclip(w4.w) * s;
      orow[i] = r;
    }
    return;
  }
  const int wid = threadIdx.x >> 6;
  const int lane = threadIdx.x & 63;
  const int row = (b - NTOK) * 4 + wid;
  const float4* __restrict__ xv = reinterpret_cast<const float4*>(x);
  float4 xl[8];
  float m = 0.0f;
  #pragma unroll
  for (int k = 0; k < 8; ++k) {
    xl[k] = xv[lane + k * 64];
    m = fmaxf(m, fmaxf(fmaxf(fabsf(xl[k].x), fabsf(xl[k].y)),
                       fmaxf(fabsf(xl[k].z), fabsf(xl[k].w))));
  }
  #pragma unroll
  for (int off = 32; off > 0; off >>= 1) m = fmaxf(m, __shfl_xor(m, off, 64));
  const float scale = fmaxf(m / 127.0f, 1e-12f);
  const float rcp = 1.0f / scale;
  #pragma unroll
  for (int k = 0; k < 8; ++k) {
    xl[k].x = fminf(fmaxf(rintf(xl[k].x * rcp), -128.0f), 127.0f) * scale;
    xl[k].y = fminf(fmaxf(rintf(xl[k].y * rcp), -128.0f), 127.0f) * scale;
    xl[k].z = fminf(fmaxf(rintf(xl[k].z * rcp), -128.0f), 127.0f) * scale;
    xl[k].w = fminf(fmaxf(rintf(xl[k].w * rcp), -128.0f), 127.0f) * scale;
  }
  const float4* __restrict__ wrow =
      reinterpret_cast<const float4*>(W + (size_t)row * DIM);
  float acc = 0.0f;
  #pragma unroll
  for (int k = 0; k < 8; ++k) {
    float4 w4 = wrow[lane + k * 64];
    acc += qclip(w4.x) * xl[k].x;
    acc += qclip(w4.y) * xl[k].y;
    acc += qclip(w4.z) * xl[k].z;
    acc += qclip(w4.w) * xl[k].w;
  }
  #pragma unroll
  for (int off = 32; off > 0; off >>= 1) acc += __shfl_down(acc, off, 64);
  if (lane == 0) out_readout[row] = acc * scales[row];
}

// ---------------------------------------------------------------------------
extern "C" void kernel_launch(void* const* d_in, const int* in_sizes, int n_in,
                              void* d_out, int out_size, void* d_ws, size_t ws_size,
                              hipStream_t stream) {
  const float* W      = (const float*)d_in[0];   // [VOCAB, DIM]
  const float* scales = (const float*)d_in[1];   // [VOCAB]
  const int*   tokens = (const int*)d_in[2];     // [NTOK]
  const float* x      = (const float*)d_in[3];   // [DIM]

  float* out_embed   = (float*)d_out;                       // [NTOK, DIM]
  float* out_readout = (float*)d_out + (size_t)NTOK * DIM;  // [VOCAB]

  if (ws_size >= BM_WORDS * sizeof(unsigned)) {
    unsigned* bm = (unsigned*)d_ws;
    bitmap_init_kernel<<<BM_WORDS / 256, 256, 0, stream>>>(bm);
    bitmap_build_kernel<<<NTOK / 256, 256, 0, stream>>>(tokens, bm);
    fused_main_kernel<<<NTOK + RO_BLOCKS, 256, 0, stream>>>(
        W, scales, tokens, x, bm, out_embed, out_readout);
  } else {
    fallback_fused_kernel<<<NTOK + RO_BLOCKS, 256, 0, stream>>>(
        W, scales, tokens, x, out_embed, out_readout);
  }
}

// Round 5
// 172.602 us; speedup vs baseline: 1.6115x; 1.6115x over previous
//
#include <hip/hip_runtime.h>

#define VOCAB 128000
#define DIM 2048
#define NTOK 8192

#define EMB_BLOCKS NTOK                      // 8192: one block per token
#define RO_BLOCKS (VOCAB / 4)                // 32000: 4 rows/block (1 row/wave)

typedef __attribute__((ext_vector_type(4))) float f4;

__device__ __forceinline__ float qclip(float w) {
  // jnp.clip(jnp.round(w), -128, 127): rintf == round-half-even == jnp.round
  return fminf(fmaxf(rintf(w), -128.0f), 127.0f);
}

// ---------------------------------------------------------------------------
// One fused kernel (R2 structure, + non-temporal hints on streaming traffic).
//   blocks [0, EMB_BLOCKS):            embed gather  (copy+dequant one row)
//   blocks [EMB_BLOCKS, +RO_BLOCKS):   readout GEMV  (1 vocab row per wave,
//                                      x-quant computed inline per wave)
// ---------------------------------------------------------------------------
__global__ __launch_bounds__(256) void fused_qembed_kernel(
    const float* __restrict__ W, const float* __restrict__ scales,
    const int* __restrict__ tokens, const float* __restrict__ x,
    float* __restrict__ out_embed, float* __restrict__ out_readout) {
  const int b = blockIdx.x;

  if (b < EMB_BLOCKS) {
    // ---- embed: out_embed[t,:] = qclip(W[tok,:]) * scales[tok] ----
    // Gather loads stay CACHED (duplicate tokens reuse L2/L3); output stores
    // are non-temporal (never re-read).
    const int t = b;
    const int tok = tokens[t];
    const float s = scales[tok];
    const f4* __restrict__ wrow =
        reinterpret_cast<const f4*>(W + (size_t)tok * DIM);
    f4* __restrict__ orow = reinterpret_cast<f4*>(out_embed + (size_t)t * DIM);
    #pragma unroll
    for (int k = 0; k < DIM / 4 / 256; ++k) {   // 2 iterations
      const int i = threadIdx.x + k * 256;
      f4 w4 = wrow[i];
      f4 r;
      r.x = qclip(w4.x) * s;
      r.y = qclip(w4.y) * s;
      r.z = qclip(w4.z) * s;
      r.w = qclip(w4.w) * s;
      __builtin_nontemporal_store(r, &orow[i]);
    }
    return;
  }

  // ---- readout: out_readout[row] = scales[row] * dot(qclip(W[row,:]), xq) --
  const int rb = b - EMB_BLOCKS;
  const int wid = threadIdx.x >> 6;
  const int lane = threadIdx.x & 63;
  const int row = rb * 4 + wid;

  // Per-wave inline activation quantization. 64 lanes x 8 f4 cover all
  // DIM=2048 elements of x; identical fp32 arithmetic in every wave ->
  // identical scale everywhere (deterministic).
  const f4* __restrict__ xv = reinterpret_cast<const f4*>(x);
  f4 xl[8];
  float m = 0.0f;
  #pragma unroll
  for (int k = 0; k < 8; ++k) {
    xl[k] = xv[lane + k * 64];
    m = fmaxf(m, fmaxf(fmaxf(fabsf(xl[k].x), fabsf(xl[k].y)),
                       fmaxf(fabsf(xl[k].z), fabsf(xl[k].w))));
  }
  #pragma unroll
  for (int off = 32; off > 0; off >>= 1) m = fmaxf(m, __shfl_xor(m, off, 64));
  const float scale = fmaxf(m / 127.0f, 1e-12f);
  const float rcp = 1.0f / scale;

  #pragma unroll
  for (int k = 0; k < 8; ++k) {
    xl[k].x = fminf(fmaxf(rintf(xl[k].x * rcp), -128.0f), 127.0f) * scale;
    xl[k].y = fminf(fmaxf(rintf(xl[k].y * rcp), -128.0f), 127.0f) * scale;
    xl[k].z = fminf(fmaxf(rintf(xl[k].z * rcp), -128.0f), 127.0f) * scale;
    xl[k].w = fminf(fmaxf(rintf(xl[k].w * rcp), -128.0f), 127.0f) * scale;
  }

  // W stream: read-once data -> non-temporal loads (don't thrash L2/L3 that
  // the concurrent embed gather + x broadcasts want).
  const f4* __restrict__ wrow = reinterpret_cast<const f4*>(W + (size_t)row * DIM);
  float acc = 0.0f;
  #pragma unroll
  for (int k = 0; k < 8; ++k) {
    f4 w4 = __builtin_nontemporal_load(&wrow[lane + k * 64]);
    acc += qclip(w4.x) * xl[k].x;
    acc += qclip(w4.y) * xl[k].y;
    acc += qclip(w4.z) * xl[k].z;
    acc += qclip(w4.w) * xl[k].w;
  }
  #pragma unroll
  for (int off = 32; off > 0; off >>= 1) acc += __shfl_down(acc, off, 64);
  if (lane == 0) out_readout[row] = acc * scales[row];
}

// ---------------------------------------------------------------------------
extern "C" void kernel_launch(void* const* d_in, const int* in_sizes, int n_in,
                              void* d_out, int out_size, void* d_ws, size_t ws_size,
                              hipStream_t stream) {
  const float* W      = (const float*)d_in[0];   // [VOCAB, DIM]
  const float* scales = (const float*)d_in[1];   // [VOCAB]
  const int*   tokens = (const int*)d_in[2];     // [NTOK]
  const float* x      = (const float*)d_in[3];   // [DIM]

  float* out_embed   = (float*)d_out;                       // [NTOK, DIM]
  float* out_readout = (float*)d_out + (size_t)NTOK * DIM;  // [VOCAB]

  fused_qembed_kernel<<<EMB_BLOCKS + RO_BLOCKS, 256, 0, stream>>>(
      W, scales, tokens, x, out_embed, out_readout);
}